// Round 18
// baseline (885.755 us; speedup 1.0000x reference)
//
#include <hip/hip_runtime.h>
#include <math.h>

// N=16384, IN=512, HID=256, E=262144.
// Z = adj @ (X@W) via fp16 split-2 MFMA (a=a1+a2, b=b1+b2; 3 products).
// GEMM path = R15 verbatim (best measured: 620.5us).
// R18: edge gather locality -- counting-sort edges by src>>7 (128 buckets,
// 128KB of Z each) so consecutive waves reuse an L2-resident src window.
// Sorted (src,dst,orig) arrays; out[orig] per edge => deterministic output.

typedef _Float16 half8v __attribute__((ext_vector_type(8)));
typedef __fp16   fp16x2 __attribute__((ext_vector_type(2)));
typedef __attribute__((ext_vector_type(4))) float floatx4;

#define NM_ (16384L * 256L)
#define KT 256        // 32-wide k-tiles per split-K half
#define NBUCK 128
#define HBLK 1024     // edges per histogram/scatter block (256 thr x 4)

static __device__ __forceinline__ void split2_pair_f16(float x0, float x1,
                                                       unsigned& q1, unsigned& q2) {
  _Float16 h0 = (_Float16)x0, h1 = (_Float16)x1;
  float r0 = x0 - (float)h0, r1 = x1 - (float)h1;
  _Float16 g0 = (_Float16)r0, g1 = (_Float16)r1;
  q1 = ((unsigned)__builtin_bit_cast(unsigned short, h1) << 16) |
       __builtin_bit_cast(unsigned short, h0);
  q2 = ((unsigned)__builtin_bit_cast(unsigned short, g1) << 16) |
       __builtin_bit_cast(unsigned short, g0);
}

static __device__ __forceinline__ void split8(const float* __restrict__ x,
                                              half8v& a0, half8v& a1) {
  union U { unsigned u[4]; half8v h; } u0, u1;
#pragma unroll
  for (int p = 0; p < 4; ++p) {
    fp16x2 h = __builtin_amdgcn_cvt_pkrtz(x[2 * p], x[2 * p + 1]);
    float r0 = x[2 * p]     - (float)h[0];   // exact
    float r1 = x[2 * p + 1] - (float)h[1];
    fp16x2 g = __builtin_amdgcn_cvt_pkrtz(r0, r1);
    u0.u[p] = __builtin_bit_cast(unsigned, h);
    u1.u[p] = __builtin_bit_cast(unsigned, g);
  }
  a0 = u0.h; a1 = u1.h;
}

static __device__ __forceinline__ void gload_lds16(const void* g, void* l) {
  __builtin_amdgcn_global_load_lds(
      (const __attribute__((address_space(1))) unsigned*)g,
      (__attribute__((address_space(3))) unsigned*)l, 16, 0, 0);
}

// ---- W[512][256] -> fragment-ready split WT: [s][kt(16)][c(4)][n(256)][8] ----
__global__ __launch_bounds__(256)
void w_split(const float* __restrict__ W, unsigned short* __restrict__ WT)
{
  const int b  = blockIdx.x;          // 64 blocks
  const int kt = b >> 2, c = b & 3;
  const int n  = threadIdx.x;
  const int k0 = kt * 32 + c * 8;
  float x[8];
#pragma unroll
  for (int j = 0; j < 8; ++j) x[j] = W[(k0 + j) * 256 + n];
  unsigned q1[4], q2[4];
#pragma unroll
  for (int p = 0; p < 4; ++p)
    split2_pair_f16(x[2 * p], x[2 * p + 1], q1[p], q2[p]);
  const long o = ((long)(kt * 4 + c) * 256 + n) * 8;
  *(uint4*)&WT[o]          = make_uint4(q1[0], q1[1], q1[2], q1[3]);
  *(uint4*)&WT[o + 131072] = make_uint4(q2[0], q2[1], q2[2], q2[3]);
}

// ---- GEMM1: XW = X @ W; epilogue writes split fragments directly ----
__global__ __launch_bounds__(256, 2)
void gemm_xw(const float* __restrict__ X, const unsigned short* __restrict__ WT,
             unsigned short* __restrict__ X1, unsigned short* __restrict__ X2)
{
  const int tid  = threadIdx.x;
  const int lane = tid & 63;
  const int w    = tid >> 6;
  const int wm = w >> 1, wn = w & 1;
  const long m0 = (long)(blockIdx.x >> 1) * 128;
  const long n0 = (long)(blockIdx.x & 1) * 128;
  const int fr = lane & 15, kc = lane >> 4;

  const unsigned short* Bq = WT + (long)kc * 2048 + ((long)n0 + wn * 64 + fr) * 8;

  const float* ap[4];
#pragma unroll
  for (int fm = 0; fm < 4; ++fm)
    ap[fm] = X + (m0 + wm * 64 + fm * 16 + fr) * 512L + kc * 8;

  floatx4 acc[4][4], accS[4][4];
#pragma unroll
  for (int i = 0; i < 4; ++i)
#pragma unroll
    for (int j = 0; j < 4; ++j) { acc[i][j] = (floatx4)0.f; accS[i][j] = (floatx4)0.f; }

  for (int t = 0; t < 16; ++t) {
    half8v bf0[4], bf1[4];
#pragma unroll
    for (int fn = 0; fn < 4; ++fn) {
      bf0[fn] = *(const half8v*)(Bq + (long)t * 8192 + fn * 128);
      bf1[fn] = *(const half8v*)(Bq + (long)t * 8192 + fn * 128 + 131072);
    }
#pragma unroll
    for (int fm = 0; fm < 4; ++fm) {
      float x[8];
      *(float4*)&x[0] = *(const float4*)(ap[fm] + t * 32);
      *(float4*)&x[4] = *(const float4*)(ap[fm] + t * 32 + 4);
      half8v a0, a1;
      split8(x, a0, a1);
#pragma unroll
      for (int fn = 0; fn < 4; ++fn) {
        floatx4 d = acc[fm][fn];
        d = __builtin_amdgcn_mfma_f32_16x16x32_f16(a0, bf0[fn], d, 0, 0, 0);
        d = __builtin_amdgcn_mfma_f32_16x16x32_f16(a0, bf1[fn], d, 0, 0, 0);
        d = __builtin_amdgcn_mfma_f32_16x16x32_f16(a1, bf0[fn], d, 0, 0, 0);
        acc[fm][fn] = d;
      }
    }
    if ((t & 3) == 3) {
#pragma unroll
      for (int i = 0; i < 4; ++i)
#pragma unroll
        for (int j = 0; j < 4; ++j) { accS[i][j] += acc[i][j]; acc[i][j] = (floatx4)0.f; }
    }
  }

  // epilogue: direct fragment-ready split write (R15)
#pragma unroll
  for (int fm = 0; fm < 4; ++fm) {
    const long K0 = m0 + wm * 64 + fm * 16 + kc * 4;
    const long kb = (K0 >> 3) * 2048 + (K0 & 7);
#pragma unroll
    for (int fn = 0; fn < 4; ++fn) {
      const long n = n0 + wn * 64 + fn * 16 + fr;
      unsigned short h4[4], g4[4];
#pragma unroll
      for (int j = 0; j < 4; ++j) {
        float v = accS[fm][fn][j];
        _Float16 h = (_Float16)v;          // RNE
        float r = v - (float)h;            // exact
        _Float16 g = (_Float16)r;
        h4[j] = __builtin_bit_cast(unsigned short, h);
        g4[j] = __builtin_bit_cast(unsigned short, g);
      }
      const long o = kb + n * 8;
      *(uint2*)&X1[o] = *(uint2*)h4;
      *(uint2*)&X2[o] = *(uint2*)g4;
    }
  }
}

// ---- GEMM2: Z-partials = adj @ XW. R15 verbatim (m97-style DMA staging). ----
__global__ __launch_bounds__(256)
void gemm_adj(const float* __restrict__ A, const unsigned short* __restrict__ Bg,
              float* __restrict__ P0, float* __restrict__ P1)
{
  __shared__ float          As[2][4096];    // 2 x 16 KB (128 rows x 32 f32)
  __shared__ unsigned short Bs[2][8192];    // 2 x 16 KB (2sp x 4c x 128n x 8)

  const int tid  = threadIdx.x;
  const int lane = tid & 63;
  const int w    = tid >> 6;          // 0..3
  const int wm = w >> 1, wn = w & 1;

  const int j   = blockIdx.x;
  const int xcd = j & 7;
  const int nh  = (j >> 3) & 1;
  const int q   = j >> 4;             // 0..31
  const int mz  = q * 8 + xcd;        // 0..255
  const long m0 = (long)(mz >> 1) * 128;
  const int  z  = mz & 1;
  const long n0 = (long)nh * 128;
  float* __restrict__ Cp = z ? P1 : P0;
  const int fr = lane & 15, kc = lane >> 4;

  const float* AgQ[4];
#pragma unroll
  for (int qq = 0; qq < 4; ++qq) {
    const int jj = (4 * w + qq) * 64 + lane;
    const int r  = jj >> 3, s = jj & 7;
    const int c  = (s >> 1) ^ (r & 3);
    AgQ[qq] = A + (m0 + r) * 16384L + (long)z * 8192 + c * 8 + (s & 1) * 4;
  }
  const unsigned short* BgQ[4];
  int bLds[4];
#pragma unroll
  for (int qq = 0; qq < 4; ++qq) {
    const int idx = 4 * w + qq;
    const int sp = idx >> 3, c = (idx >> 1) & 3, hf = idx & 1;
    BgQ[qq] = Bg + (long)sp * NM_ + ((long)c * 256 + n0 + hf * 64 + lane) * 8;
    bLds[qq] = ((sp * 4 + c) * 128 + hf * 64) * 8;
  }

  int aOff[4][2];
#pragma unroll
  for (int fm = 0; fm < 4; ++fm) {
    const int R = wm * 64 + fm * 16 + fr;
#pragma unroll
    for (int h = 0; h < 2; ++h)
      aOff[fm][h] = R * 32 + ((kc ^ (fr & 3)) * 2 + h) * 4;
  }
  int bOff[4][2];
#pragma unroll
  for (int fn = 0; fn < 4; ++fn)
#pragma unroll
    for (int sp = 0; sp < 2; ++sp)
      bOff[fn][sp] = ((sp * 4 + kc) * 128 + wn * 64 + fn * 16 + fr) * 8;

  floatx4 acc[4][4], accS[4][4];
#pragma unroll
  for (int i = 0; i < 4; ++i)
#pragma unroll
    for (int jx = 0; jx < 4; ++jx) { acc[i][jx] = (floatx4)0.f; accS[i][jx] = (floatx4)0.f; }

#define STAGE(TT, BUF)                                                            \
  {                                                                               \
    const long koA = (long)((TT) & (KT - 1)) * 32;                                \
    const long koB = (long)((TT) & (KT - 1)) * 8192 + (long)z * 2097152;          \
    _Pragma("unroll")                                                             \
    for (int qq = 0; qq < 4; ++qq)                                                \
      gload_lds16(AgQ[qq] + koA, &As[BUF][(4 * w + qq) * 256]);                   \
    _Pragma("unroll")                                                             \
    for (int qq = 0; qq < 4; ++qq)                                                \
      gload_lds16(BgQ[qq] + koB, &Bs[BUF][bLds[qq]]);                             \
  }

  STAGE(0, 0);
  __syncthreads();

  int buf = 0;
  for (int t = 0; t < KT; ++t) {
    STAGE(t + 1, buf ^ 1);
    __builtin_amdgcn_sched_barrier(0);
    half8v bf[2][4];
#pragma unroll
    for (int fn = 0; fn < 4; ++fn) {
      bf[0][fn] = *(const half8v*)&Bs[buf][bOff[fn][0]];
      bf[1][fn] = *(const half8v*)&Bs[buf][bOff[fn][1]];
    }
#pragma unroll
    for (int fm = 0; fm < 4; ++fm) {
      float x[8];
      *(float4*)&x[0] = *(const float4*)&As[buf][aOff[fm][0]];
      *(float4*)&x[4] = *(const float4*)&As[buf][aOff[fm][1]];
      half8v a0, a1;
      split8(x, a0, a1);
#pragma unroll
      for (int fn = 0; fn < 4; ++fn) {
        floatx4 d = acc[fm][fn];
        d = __builtin_amdgcn_mfma_f32_16x16x32_f16(a0, bf[0][fn], d, 0, 0, 0);
        d = __builtin_amdgcn_mfma_f32_16x16x32_f16(a0, bf[1][fn], d, 0, 0, 0);
        d = __builtin_amdgcn_mfma_f32_16x16x32_f16(a1, bf[0][fn], d, 0, 0, 0);
        acc[fm][fn] = d;
      }
    }
    if ((t & 31) == 31) {
#pragma unroll
      for (int i = 0; i < 4; ++i)
#pragma unroll
        for (int jx = 0; jx < 4; ++jx) { accS[i][jx] += acc[i][jx]; acc[i][jx] = (floatx4)0.f; }
    }
    __syncthreads();
    buf ^= 1;
  }

#pragma unroll
  for (int fm = 0; fm < 4; ++fm)
#pragma unroll
    for (int fn = 0; fn < 4; ++fn) {
      const long col  = n0 + wn * 64 + fn * 16 + fr;
      const long rowb = m0 + wm * 64 + fm * 16 + kc * 4;
#pragma unroll
      for (int jj = 0; jj < 4; ++jj)
        Cp[(rowb + jj) * 256 + col] = accS[fm][fn][jj];
    }
#undef STAGE
}

// ---------------- P1 += P0 ----------------
__global__ __launch_bounds__(256)
void reduce_add(const float* __restrict__ P0, float* __restrict__ P1, long n4)
{
  long i = (long)blockIdx.x * 256 + threadIdx.x;
  const long stride = (long)gridDim.x * 256;
  for (; i < n4; i += stride) {
    float4 a = ((const float4*)P0)[i];
    float4 b = ((const float4*)P1)[i];
    b.x += a.x; b.y += a.y; b.z += a.z; b.w += a.w;
    ((float4*)P1)[i] = b;
  }
}

// ---------------- edge sort (counting sort by src>>7, 128 buckets) ----------
// Edge i in [0, 2E): (src,dst) from te (i<E) or fe (i-E). Bucket = src>>7.
// k1: per-block LDS histograms -> gh[bucket*nblk + blk]
// k2: single block: exclusive scan over gh (bucket-major) in place
// k3: scatter via LDS cursors (gh gives block base per bucket)
__global__ __launch_bounds__(256)
void edge_hist(const int* __restrict__ te, const int* __restrict__ fe,
               int E, int nblk, int* __restrict__ gh)
{
  __shared__ int h[NBUCK];
  const int tid = threadIdx.x;
  const int blk = blockIdx.x;
  if (tid < NBUCK) h[tid] = 0;
  __syncthreads();
  const long base = (long)blk * HBLK;
  const long lim = 2L * E;
#pragma unroll
  for (int i = 0; i < 4; ++i) {
    const long e = base + tid + 256 * i;
    if (e < lim) {
      const int src = (e < E) ? te[2 * e] : fe[2 * (e - E)];
      atomicAdd(&h[src >> 7], 1);
    }
  }
  __syncthreads();
  if (tid < NBUCK) gh[tid * nblk + blk] = h[tid];
}

__global__ __launch_bounds__(256)
void edge_scan(int* __restrict__ gh, int n)   // n = NBUCK*nblk, single block
{
  __shared__ int carry;
  const int tid = threadIdx.x;
  if (tid == 0) carry = 0;
  __syncthreads();
  // serial-chunked exclusive scan: 256 elems per chunk
  for (int base = 0; base < n; base += 256) {
    int v = (base + tid < n) ? gh[base + tid] : 0;
    // inclusive scan of v across 256 threads via LDS
    __shared__ int s[256];
    s[tid] = v;
    __syncthreads();
    for (int off = 1; off < 256; off <<= 1) {
      int add = (tid >= off) ? s[tid - off] : 0;
      __syncthreads();
      s[tid] += add;
      __syncthreads();
    }
    const int incl = s[tid];
    const int excl = incl - v + carry;
    if (base + tid < n) gh[base + tid] = excl;
    __syncthreads();
    if (tid == 255) carry = incl + carry - 0;   // carry += chunk total
    __syncthreads();
  }
}

__global__ __launch_bounds__(256)
void edge_scatter(const int* __restrict__ te, const int* __restrict__ fe,
                  int E, int nblk, const int* __restrict__ gh,
                  int2* __restrict__ se, int* __restrict__ oi)
{
  __shared__ int cur[NBUCK];
  const int tid = threadIdx.x;
  const int blk = blockIdx.x;
  if (tid < NBUCK) cur[tid] = gh[tid * nblk + blk];
  __syncthreads();
  const long base = (long)blk * HBLK;
  const long lim = 2L * E;
#pragma unroll
  for (int i = 0; i < 4; ++i) {
    const long e = base + tid + 256 * i;
    if (e < lim) {
      int src, dst;
      if (e < E) { src = te[2 * e]; dst = te[2 * e + 1]; }
      else       { src = fe[2 * (e - E)]; dst = fe[2 * (e - E) + 1]; }
      const int slot = atomicAdd(&cur[src >> 7], 1);
      se[slot] = make_int2(src, dst);
      oi[slot] = (int)e;
    }
  }
}

// ---------------- edge scoring (sorted order) ----------------
__global__ __launch_bounds__(256)
void edge_score(const float* __restrict__ Z, const float* __restrict__ w2,
                const int2* __restrict__ se, const int* __restrict__ oi,
                long nw, float* __restrict__ out)
{
  const long gtid = (long)blockIdx.x * 256 + threadIdx.x;
  const long wid = gtid >> 6;
  const int lane = threadIdx.x & 63;
  if (wid >= nw) return;
  const int2 ed = se[wid];
  const float4 a = ((const float4*)(Z + (long)ed.x * 256))[lane];
  const float4 b = ((const float4*)(Z + (long)ed.y * 256))[lane];
  const float4 w = ((const float4*)w2)[lane];
  float s = a.x * b.x * w.x + a.y * b.y * w.y + a.z * b.z * w.z + a.w * b.w * w.w;
#pragma unroll
  for (int off = 32; off > 0; off >>= 1) s += __shfl_down(s, off);
  if (lane == 0) out[oi[wid]] = 1.0f / (1.0f + expf(-s));
}

extern "C" void kernel_launch(void* const* d_in, const int* in_sizes, int n_in,
                              void* d_out, int out_size, void* d_ws, size_t ws_size,
                              hipStream_t stream)
{
  const float* X   = (const float*)d_in[0];
  const float* adj = (const float*)d_in[1];
  const float* W   = (const float*)d_in[2];
  const float* W2  = (const float*)d_in[3];
  const int*   te  = (const int*)d_in[4];
  const int*   fe  = (const int*)d_in[5];

  const int E = in_sizes[4] / 2;
  const long nw = 2L * E;
  const int nblk = (int)((nw + HBLK - 1) / HBLK);   // 512 for E=262144

  float* ws = (float*)d_ws;
  float* P0 = ws;                      // split-K partial 0
  float* P1 = ws + NM_;                // final Z (after reduce_add)
  unsigned short* X1 = (unsigned short*)(ws + 2 * NM_);
  unsigned short* X2 = X1 + NM_;
  unsigned short* WT = X2 + NM_;       // 0.5 MB
  int2* se = (int2*)(WT + 2 * 131072); // sorted (src,dst), 4.2 MB
  int*  oi = (int*)(se + nw);          // orig index, 2.1 MB
  int*  gh = oi + nw;                  // histogram/scan, NBUCK*nblk ints
  // total ws ~ 57.5 MB

  dim3 b256(256);
  w_split<<<dim3(64), b256, 0, stream>>>(W, WT);
  gemm_xw<<<dim3(256), b256, 0, stream>>>(X, WT, X1, X2);
  gemm_adj<<<dim3(512), b256, 0, stream>>>(adj, X1, P0, P1);
  reduce_add<<<dim3(2048), b256, 0, stream>>>(P0, P1, NM_ / 4);
  // edge sort + score
  edge_hist<<<dim3(nblk), b256, 0, stream>>>(te, fe, E, nblk, gh);
  edge_scan<<<dim3(1), b256, 0, stream>>>(gh, NBUCK * nblk);
  edge_scatter<<<dim3(nblk), b256, 0, stream>>>(te, fe, E, nblk, gh, se, oi);
  const int nblocks = (int)((nw + 3) / 4);
  edge_score<<<dim3(nblocks), b256, 0, stream>>>(P1, W2, se, oi, nw, (float*)d_out);
}

// Round 19
// 625.025 us; speedup vs baseline: 1.4172x; 1.4172x over previous
//
#include <hip/hip_runtime.h>
#include <math.h>

// N=16384, IN=512, HID=256, E=262144.
// Z = adj @ (X@W) via fp16 split-2 MFMA (a=a1+a2, b=b1+b2; 3 products).
// R19 = R15 verbatim (best measured: 620.5us). R16 (bottom-staging), R17
// (counted vmcnt: within noise), R18 (edge sort: +265us) all explored;
// this 2-barrier m97-style DMA pipeline is the proven optimum reachable.

typedef _Float16 half8v __attribute__((ext_vector_type(8)));
typedef __fp16   fp16x2 __attribute__((ext_vector_type(2)));
typedef __attribute__((ext_vector_type(4))) float floatx4;

#define NM_ (16384L * 256L)
#define KT 256   // 32-wide k-tiles per split-K half

static __device__ __forceinline__ void split2_pair_f16(float x0, float x1,
                                                       unsigned& q1, unsigned& q2) {
  _Float16 h0 = (_Float16)x0, h1 = (_Float16)x1;
  float r0 = x0 - (float)h0, r1 = x1 - (float)h1;
  _Float16 g0 = (_Float16)r0, g1 = (_Float16)r1;
  q1 = ((unsigned)__builtin_bit_cast(unsigned short, h1) << 16) |
       __builtin_bit_cast(unsigned short, h0);
  q2 = ((unsigned)__builtin_bit_cast(unsigned short, g1) << 16) |
       __builtin_bit_cast(unsigned short, g0);
}

static __device__ __forceinline__ void split8(const float* __restrict__ x,
                                              half8v& a0, half8v& a1) {
  union U { unsigned u[4]; half8v h; } u0, u1;
#pragma unroll
  for (int p = 0; p < 4; ++p) {
    fp16x2 h = __builtin_amdgcn_cvt_pkrtz(x[2 * p], x[2 * p + 1]);
    float r0 = x[2 * p]     - (float)h[0];   // exact
    float r1 = x[2 * p + 1] - (float)h[1];
    fp16x2 g = __builtin_amdgcn_cvt_pkrtz(r0, r1);
    u0.u[p] = __builtin_bit_cast(unsigned, h);
    u1.u[p] = __builtin_bit_cast(unsigned, g);
  }
  a0 = u0.h; a1 = u1.h;
}

static __device__ __forceinline__ void gload_lds16(const void* g, void* l) {
  __builtin_amdgcn_global_load_lds(
      (const __attribute__((address_space(1))) unsigned*)g,
      (__attribute__((address_space(3))) unsigned*)l, 16, 0, 0);
}

// ---- W[512][256] -> fragment-ready split WT: [s][kt(16)][c(4)][n(256)][8] ----
__global__ __launch_bounds__(256)
void w_split(const float* __restrict__ W, unsigned short* __restrict__ WT)
{
  const int b  = blockIdx.x;          // 64 blocks
  const int kt = b >> 2, c = b & 3;
  const int n  = threadIdx.x;
  const int k0 = kt * 32 + c * 8;
  float x[8];
#pragma unroll
  for (int j = 0; j < 8; ++j) x[j] = W[(k0 + j) * 256 + n];
  unsigned q1[4], q2[4];
#pragma unroll
  for (int p = 0; p < 4; ++p)
    split2_pair_f16(x[2 * p], x[2 * p + 1], q1[p], q2[p]);
  const long o = ((long)(kt * 4 + c) * 256 + n) * 8;
  *(uint4*)&WT[o]          = make_uint4(q1[0], q1[1], q1[2], q1[3]);
  *(uint4*)&WT[o + 131072] = make_uint4(q2[0], q2[1], q2[2], q2[3]);
}

// ---- GEMM1: XW = X @ W; epilogue writes split fragments directly ----
__global__ __launch_bounds__(256, 2)
void gemm_xw(const float* __restrict__ X, const unsigned short* __restrict__ WT,
             unsigned short* __restrict__ X1, unsigned short* __restrict__ X2)
{
  const int tid  = threadIdx.x;
  const int lane = tid & 63;
  const int w    = tid >> 6;
  const int wm = w >> 1, wn = w & 1;
  const long m0 = (long)(blockIdx.x >> 1) * 128;
  const long n0 = (long)(blockIdx.x & 1) * 128;
  const int fr = lane & 15, kc = lane >> 4;

  const unsigned short* Bq = WT + (long)kc * 2048 + ((long)n0 + wn * 64 + fr) * 8;

  const float* ap[4];
#pragma unroll
  for (int fm = 0; fm < 4; ++fm)
    ap[fm] = X + (m0 + wm * 64 + fm * 16 + fr) * 512L + kc * 8;

  floatx4 acc[4][4], accS[4][4];
#pragma unroll
  for (int i = 0; i < 4; ++i)
#pragma unroll
    for (int j = 0; j < 4; ++j) { acc[i][j] = (floatx4)0.f; accS[i][j] = (floatx4)0.f; }

  for (int t = 0; t < 16; ++t) {
    half8v bf0[4], bf1[4];
#pragma unroll
    for (int fn = 0; fn < 4; ++fn) {
      bf0[fn] = *(const half8v*)(Bq + (long)t * 8192 + fn * 128);
      bf1[fn] = *(const half8v*)(Bq + (long)t * 8192 + fn * 128 + 131072);
    }
#pragma unroll
    for (int fm = 0; fm < 4; ++fm) {
      float x[8];
      *(float4*)&x[0] = *(const float4*)(ap[fm] + t * 32);
      *(float4*)&x[4] = *(const float4*)(ap[fm] + t * 32 + 4);
      half8v a0, a1;
      split8(x, a0, a1);
#pragma unroll
      for (int fn = 0; fn < 4; ++fn) {
        floatx4 d = acc[fm][fn];
        d = __builtin_amdgcn_mfma_f32_16x16x32_f16(a0, bf0[fn], d, 0, 0, 0);
        d = __builtin_amdgcn_mfma_f32_16x16x32_f16(a0, bf1[fn], d, 0, 0, 0);
        d = __builtin_amdgcn_mfma_f32_16x16x32_f16(a1, bf0[fn], d, 0, 0, 0);
        acc[fm][fn] = d;
      }
    }
    if ((t & 3) == 3) {
#pragma unroll
      for (int i = 0; i < 4; ++i)
#pragma unroll
        for (int j = 0; j < 4; ++j) { accS[i][j] += acc[i][j]; acc[i][j] = (floatx4)0.f; }
    }
  }

  // epilogue: direct fragment-ready split write
#pragma unroll
  for (int fm = 0; fm < 4; ++fm) {
    const long K0 = m0 + wm * 64 + fm * 16 + kc * 4;
    const long kb = (K0 >> 3) * 2048 + (K0 & 7);
#pragma unroll
    for (int fn = 0; fn < 4; ++fn) {
      const long n = n0 + wn * 64 + fn * 16 + fr;
      unsigned short h4[4], g4[4];
#pragma unroll
      for (int j = 0; j < 4; ++j) {
        float v = accS[fm][fn][j];
        _Float16 h = (_Float16)v;          // RNE
        float r = v - (float)h;            // exact
        _Float16 g = (_Float16)r;
        h4[j] = __builtin_bit_cast(unsigned short, h);
        g4[j] = __builtin_bit_cast(unsigned short, g);
      }
      const long o = kb + n * 8;
      *(uint2*)&X1[o] = *(uint2*)h4;
      *(uint2*)&X2[o] = *(uint2*)g4;
    }
  }
}

// ---- GEMM2: Z-partials = adj @ XW. m97-style: all staging via gload_lds. ----
// 512 blocks x 256 thr (4 waves 2x2, wave=64x64). BM=128, BN=128, splitK=2.
__global__ __launch_bounds__(256)
void gemm_adj(const float* __restrict__ A, const unsigned short* __restrict__ Bg,
              float* __restrict__ P0, float* __restrict__ P1)
{
  __shared__ float          As[2][4096];    // 2 x 16 KB (128 rows x 32 f32)
  __shared__ unsigned short Bs[2][8192];    // 2 x 16 KB (2sp x 4c x 128n x 8)

  const int tid  = threadIdx.x;
  const int lane = tid & 63;
  const int w    = tid >> 6;          // 0..3
  const int wm = w >> 1, wn = w & 1;

  const int j   = blockIdx.x;
  const int xcd = j & 7;
  const int nh  = (j >> 3) & 1;
  const int q   = j >> 4;             // 0..31
  const int mz  = q * 8 + xcd;        // 0..255
  const long m0 = (long)(mz >> 1) * 128;
  const int  z  = mz & 1;
  const long n0 = (long)nh * 128;
  float* __restrict__ Cp = z ? P1 : P0;
  const int fr = lane & 15, kc = lane >> 4;

  const float* AgQ[4];
#pragma unroll
  for (int qq = 0; qq < 4; ++qq) {
    const int jj = (4 * w + qq) * 64 + lane;
    const int r  = jj >> 3, s = jj & 7;
    const int c  = (s >> 1) ^ (r & 3);
    AgQ[qq] = A + (m0 + r) * 16384L + (long)z * 8192 + c * 8 + (s & 1) * 4;
  }
  const unsigned short* BgQ[4];
  int bLds[4];
#pragma unroll
  for (int qq = 0; qq < 4; ++qq) {
    const int idx = 4 * w + qq;
    const int sp = idx >> 3, c = (idx >> 1) & 3, hf = idx & 1;
    BgQ[qq] = Bg + (long)sp * NM_ + ((long)c * 256 + n0 + hf * 64 + lane) * 8;
    bLds[qq] = ((sp * 4 + c) * 128 + hf * 64) * 8;
  }

  int aOff[4][2];
#pragma unroll
  for (int fm = 0; fm < 4; ++fm) {
    const int R = wm * 64 + fm * 16 + fr;
#pragma unroll
    for (int h = 0; h < 2; ++h)
      aOff[fm][h] = R * 32 + ((kc ^ (fr & 3)) * 2 + h) * 4;
  }
  int bOff[4][2];
#pragma unroll
  for (int fn = 0; fn < 4; ++fn)
#pragma unroll
    for (int sp = 0; sp < 2; ++sp)
      bOff[fn][sp] = ((sp * 4 + kc) * 128 + wn * 64 + fn * 16 + fr) * 8;

  floatx4 acc[4][4], accS[4][4];
#pragma unroll
  for (int i = 0; i < 4; ++i)
#pragma unroll
    for (int jx = 0; jx < 4; ++jx) { acc[i][jx] = (floatx4)0.f; accS[i][jx] = (floatx4)0.f; }

#define STAGE(TT, BUF)                                                            \
  {                                                                               \
    const long koA = (long)((TT) & (KT - 1)) * 32;                                \
    const long koB = (long)((TT) & (KT - 1)) * 8192 + (long)z * 2097152;          \
    _Pragma("unroll")                                                             \
    for (int qq = 0; qq < 4; ++qq)                                                \
      gload_lds16(AgQ[qq] + koA, &As[BUF][(4 * w + qq) * 256]);                   \
    _Pragma("unroll")                                                             \
    for (int qq = 0; qq < 4; ++qq)                                                \
      gload_lds16(BgQ[qq] + koB, &Bs[BUF][bLds[qq]]);                             \
  }

  STAGE(0, 0);
  __syncthreads();

  int buf = 0;
  for (int t = 0; t < KT; ++t) {
    STAGE(t + 1, buf ^ 1);
    __builtin_amdgcn_sched_barrier(0);
    half8v bf[2][4];
#pragma unroll
    for (int fn = 0; fn < 4; ++fn) {
      bf[0][fn] = *(const half8v*)&Bs[buf][bOff[fn][0]];
      bf[1][fn] = *(const half8v*)&Bs[buf][bOff[fn][1]];
    }
#pragma unroll
    for (int fm = 0; fm < 4; ++fm) {
      float x[8];
      *(float4*)&x[0] = *(const float4*)&As[buf][aOff[fm][0]];
      *(float4*)&x[4] = *(const float4*)&As[buf][aOff[fm][1]];
      half8v a0, a1;
      split8(x, a0, a1);
#pragma unroll
      for (int fn = 0; fn < 4; ++fn) {
        floatx4 d = acc[fm][fn];
        d = __builtin_amdgcn_mfma_f32_16x16x32_f16(a0, bf[0][fn], d, 0, 0, 0);
        d = __builtin_amdgcn_mfma_f32_16x16x32_f16(a0, bf[1][fn], d, 0, 0, 0);
        d = __builtin_amdgcn_mfma_f32_16x16x32_f16(a1, bf[0][fn], d, 0, 0, 0);
        acc[fm][fn] = d;
      }
    }
    if ((t & 31) == 31) {
#pragma unroll
      for (int i = 0; i < 4; ++i)
#pragma unroll
        for (int jx = 0; jx < 4; ++jx) { accS[i][jx] += acc[i][jx]; acc[i][jx] = (floatx4)0.f; }
    }
    __syncthreads();
    buf ^= 1;
  }

#pragma unroll
  for (int fm = 0; fm < 4; ++fm)
#pragma unroll
    for (int fn = 0; fn < 4; ++fn) {
      const long col  = n0 + wn * 64 + fn * 16 + fr;
      const long rowb = m0 + wm * 64 + fm * 16 + kc * 4;
#pragma unroll
      for (int jj = 0; jj < 4; ++jj)
        Cp[(rowb + jj) * 256 + col] = accS[fm][fn][jj];
    }
#undef STAGE
}

// ---------------- P1 += P0 ----------------
__global__ __launch_bounds__(256)
void reduce_add(const float* __restrict__ P0, float* __restrict__ P1, long n4)
{
  long i = (long)blockIdx.x * 256 + threadIdx.x;
  const long stride = (long)gridDim.x * 256;
  for (; i < n4; i += stride) {
    float4 a = ((const float4*)P0)[i];
    float4 b = ((const float4*)P1)[i];
    b.x += a.x; b.y += a.y; b.z += a.z; b.w += a.w;
    ((float4*)P1)[i] = b;
  }
}

// ---------------- edge scoring ----------------
__global__ __launch_bounds__(256)
void edge_score(const float* __restrict__ Z, const float* __restrict__ w2,
                const int* __restrict__ te, const int* __restrict__ fe,
                int E, float* __restrict__ out)
{
  const long gtid = (long)blockIdx.x * 256 + threadIdx.x;
  const long wid = gtid >> 6;
  const int lane = threadIdx.x & 63;
  if (wid >= 2L * E) return;
  const int* ep = (wid < E) ? (te + 2 * wid) : (fe + 2 * (wid - E));
  const int src = ep[0];
  const int dst = ep[1];
  const float4 a = ((const float4*)(Z + (long)src * 256))[lane];
  const float4 b = ((const float4*)(Z + (long)dst * 256))[lane];
  const float4 w = ((const float4*)w2)[lane];
  float s = a.x * b.x * w.x + a.y * b.y * w.y + a.z * b.z * w.z + a.w * b.w * w.w;
#pragma unroll
  for (int off = 32; off > 0; off >>= 1) s += __shfl_down(s, off);
  if (lane == 0) out[wid] = 1.0f / (1.0f + expf(-s));
}

extern "C" void kernel_launch(void* const* d_in, const int* in_sizes, int n_in,
                              void* d_out, int out_size, void* d_ws, size_t ws_size,
                              hipStream_t stream)
{
  const float* X   = (const float*)d_in[0];
  const float* adj = (const float*)d_in[1];
  const float* W   = (const float*)d_in[2];
  const float* W2  = (const float*)d_in[3];
  const int*   te  = (const int*)d_in[4];
  const int*   fe  = (const int*)d_in[5];

  const int E = in_sizes[4] / 2;

  float* ws = (float*)d_ws;
  float* P0 = ws;                      // split-K partial 0
  float* P1 = ws + NM_;                // final Z (after reduce_add)
  unsigned short* X1 = (unsigned short*)(ws + 2 * NM_);
  unsigned short* X2 = X1 + NM_;
  unsigned short* WT = X2 + NM_;       // 0.5 MB
  // total ws: 2*NM*4 + 2*NM*2 + 0.5MB ~ 50.9 MB

  dim3 b256(256);
  w_split<<<dim3(64), b256, 0, stream>>>(W, WT);
  gemm_xw<<<dim3(256), b256, 0, stream>>>(X, WT, X1, X2);   // fragments direct
  gemm_adj<<<dim3(512), b256, 0, stream>>>(adj, X1, P0, P1);
  reduce_add<<<dim3(2048), b256, 0, stream>>>(P0, P1, NM_ / 4);
  const long nwaves = 2L * E;
  const int nblocks = (int)((nwaves + 3) / 4);
  edge_score<<<dim3(nblocks), b256, 0, stream>>>(P1, W2, te, fe, E, (float*)d_out);
}